// Round 4
// baseline (295.638 us; speedup 1.0000x reference)
//
#include <hip/hip_runtime.h>

// WaveletFeatureAugmentation via composite linear map:
//   aug = W @ wavedec9(x) + b == CM @ x + b   (CM = [14][4096], built once).
// Kernel 1 (verified round 3): builds CM in d_ws via the adjoint cascade.
// Kernel 2: fused stream. 16 waves/block; wave w owns a 256-col stripe with
// its CM slice in registers (56 VGPRs). Each wave processes 16 rows with NO
// barriers (per-wave butterfly reduce -> LDS partials), then ONE syncthreads
// and a 224-thread combine. Latency overlaps across decoupled waves.

#define ROWS 16384          // 32*512
#define N0   4096
#define OUTW 4110           // 4096 + 14
#define RPB  16             // rows per block

__device__ __constant__ float c_dlo[8] = {
    -0.010597401784997278f,  0.032883011666982945f,
     0.030841381835986965f, -0.18703481171888114f,
    -0.02798376941698385f,   0.6308807679295904f,
     0.7148465705525415f,    0.23037781330885523f};

// ---- CM builder (unchanged from round 3, verified) ----
__device__ __forceinline__ float adj_contrib(const float* __restrict__ g,
                                             int t, int nout) {
    int i0 = t >> 1;        if (i0 < 0) i0 = 0;
    int i1 = (t + 6) >> 1;  if (i1 > nout - 1) i1 = nout - 1;
    float acc = 0.f;
    for (int i = i0; i <= i1; ++i)
        acc = fmaf(g[i], c_dlo[2 * i + 1 - t], acc);
    return acc;
}

__global__ __launch_bounds__(256) void build_cm_kernel(
    const float* __restrict__ W, float* __restrict__ cm)
{
    __shared__ float A[4096];
    __shared__ float B[2051];
    const int o = blockIdx.x, tid = threadIdx.x;
    if (tid < 14) B[tid] = W[o * 14 + tid];
    __syncthreads();
    const int ns[10] = {14, 22, 38, 70, 134, 262, 518, 1029, 2051, 4096};
    float* g = B;
    float* h = A;
    for (int lev = 1; lev <= 9; ++lev) {
        const int n = ns[lev], nout = ns[lev - 1];
        const int s2 = 2 * (n - nout);
        for (int s = tid; s < n; s += 256) {
            float v = adj_contrib(g, s, nout);
            if (s <= 5)  v += adj_contrib(g, -1 - s, nout);
            if (s >= s2) v += adj_contrib(g, 2 * n - 1 - s, nout);
            h[s] = v;
        }
        __syncthreads();
        float* t2 = g; g = h; h = t2;
    }
    for (int c = tid; c < 4096; c += 256) cm[o * 4096 + c] = g[c];
}

// ---- fused streaming kernel ----
__global__ __launch_bounds__(1024) void wavelet_aug_fused(
    const float* __restrict__ x, const float* __restrict__ cm,
    const float* __restrict__ b, float* __restrict__ out)
{
    __shared__ float parts[16][RPB][14];        // [wave][row][o], 14.3 KB
    const int tid  = threadIdx.x;
    const int wave = tid >> 6;
    const int lane = tid & 63;
    const int col  = (wave << 8) + (lane << 2); // wave = 256-col stripe

    float4 cmv[14];
    #pragma unroll
    for (int o = 0; o < 14; ++o)
        cmv[o] = *reinterpret_cast<const float4*>(cm + o * N0 + col);

    const int row0 = blockIdx.x * RPB;
    const float* xp = x + (size_t)row0 * N0 + col;

    float4 xa = *reinterpret_cast<const float4*>(xp);   // row 0
    #pragma unroll 1
    for (int r = 0; r < RPB; ++r) {
        float4 xn;
        if (r < RPB - 1)
            xn = *reinterpret_cast<const float4*>(xp + (size_t)(r + 1) * N0);

        // passthrough (out rows 8B-aligned -> float2)
        float* orow = out + (size_t)(row0 + r) * OUTW + col;
        reinterpret_cast<float2*>(orow)[0] = make_float2(xa.x, xa.y);
        reinterpret_cast<float2*>(orow)[1] = make_float2(xa.z, xa.w);

        float acc[14];
        #pragma unroll
        for (int o = 0; o < 14; ++o) {
            float v = xa.x * cmv[o].x;
            v = fmaf(xa.y, cmv[o].y, v);
            v = fmaf(xa.z, cmv[o].z, v);
            v = fmaf(xa.w, cmv[o].w, v);
            acc[o] = v;
        }
        #pragma unroll
        for (int o = 0; o < 14; ++o) {
            float v = acc[o];
            v += __shfl_xor(v, 1);  v += __shfl_xor(v, 2);
            v += __shfl_xor(v, 4);  v += __shfl_xor(v, 8);
            v += __shfl_xor(v, 16); v += __shfl_xor(v, 32);
            acc[o] = v;
        }
        if (lane == 0) {
            #pragma unroll
            for (int o = 0; o < 14; ++o) parts[wave][r][o] = acc[o];
        }
        xa = xn;
    }
    __syncthreads();

    // combine: 224 threads, one (row, o) each; fixed summation order.
    if (tid < RPB * 14) {
        const int r = tid / 14, o = tid - r * 14;
        float s = b[o];
        #pragma unroll
        for (int w = 0; w < 16; ++w) s += parts[w][r][o];
        out[(size_t)(row0 + r) * OUTW + N0 + o] = s;
    }
}

extern "C" void kernel_launch(void* const* d_in, const int* in_sizes, int n_in,
                              void* d_out, int out_size, void* d_ws, size_t ws_size,
                              hipStream_t stream) {
    const float* x = (const float*)d_in[0];   // [32,512,4096]
    const float* W = (const float*)d_in[1];   // [14,14]
    const float* b = (const float*)d_in[2];   // [14]
    float* out = (float*)d_out;               // [32,512,4110]
    float* cm  = (float*)d_ws;                // [14][4096]

    build_cm_kernel<<<14, 256, 0, stream>>>(W, cm);
    wavelet_aug_fused<<<ROWS / RPB, 1024, 0, stream>>>(x, cm, b, out);
}

// Round 6
// 160.019 us; speedup vs baseline: 1.8475x; 1.8475x over previous
//
#include <hip/hip_runtime.h>

// WaveletFeatureAugmentation via composite linear map (CM = W @ cascade,
// [14][4096], built once in d_ws — verified rounds 3/4, absmax 0.031).
// Main kernel: 1024 thr (16 waves) / block, 32 rows/block, wave owns a fixed
// 256-col stripe with its CM slice in 56 VGPRs. 4-deep row pipeline keeps
// 4 independent 16B loads in flight per lane (Little's law). Reduction:
// DPP (xor1/2 quad_perm, half-mirror, mirror) = 0 DS ops, then only
// xor16/xor32 shuffles -> DS-pipe load cut ~3x vs round 4.

#define ROWS  16384          // 32*512
#define N0    4096
#define OUTW  4110           // 4096 + 14
#define RPB   32             // rows per block
#define BATCH 4
#define NBATCH (RPB / BATCH)

__device__ __constant__ float c_dlo[8] = {
    -0.010597401784997278f,  0.032883011666982945f,
     0.030841381835986965f, -0.18703481171888114f,
    -0.02798376941698385f,   0.6308807679295904f,
     0.7148465705525415f,    0.23037781330885523f};

// ---- CM builder (unchanged from round 3, verified) ----
__device__ __forceinline__ float adj_contrib(const float* __restrict__ g,
                                             int t, int nout) {
    int i0 = t >> 1;        if (i0 < 0) i0 = 0;
    int i1 = (t + 6) >> 1;  if (i1 > nout - 1) i1 = nout - 1;
    float acc = 0.f;
    for (int i = i0; i <= i1; ++i)
        acc = fmaf(g[i], c_dlo[2 * i + 1 - t], acc);
    return acc;
}

__global__ __launch_bounds__(256) void build_cm_kernel(
    const float* __restrict__ W, float* __restrict__ cm)
{
    __shared__ float A[4096];
    __shared__ float B[2051];
    const int o = blockIdx.x, tid = threadIdx.x;
    if (tid < 14) B[tid] = W[o * 14 + tid];
    __syncthreads();
    const int ns[10] = {14, 22, 38, 70, 134, 262, 518, 1029, 2051, 4096};
    float* g = B;
    float* h = A;
    for (int lev = 1; lev <= 9; ++lev) {
        const int n = ns[lev], nout = ns[lev - 1];
        const int s2 = 2 * (n - nout);
        for (int s = tid; s < n; s += 256) {
            float v = adj_contrib(g, s, nout);
            if (s <= 5)  v += adj_contrib(g, -1 - s, nout);
            if (s >= s2) v += adj_contrib(g, 2 * n - 1 - s, nout);
            h[s] = v;
        }
        __syncthreads();
        float* t2 = g; g = h; h = t2;
    }
    for (int c = tid; c < 4096; c += 256) cm[o * 4096 + c] = g[c];
}

// DPP butterfly-add stage (pure VALU, no DS pipe). For a commutative sum,
// half-mirror / mirror substitute for xor4 / xor8: after xor1+xor2 every
// lane of a quad holds the quad sum, so any cross-quad pairing works.
// CTRL must be an immediate -> template parameter.
template<int CTRL>
__device__ __forceinline__ float dpp_add(float v) {
    int t = __builtin_amdgcn_update_dpp(0, __float_as_int(v), CTRL, 0xF, 0xF, true);
    return v + __int_as_float(t);
}

__global__ __launch_bounds__(1024) void wavelet_aug_fused(
    const float* __restrict__ x, const float* __restrict__ cm,
    const float* __restrict__ b, float* __restrict__ out)
{
    __shared__ float parts[16][RPB][16];   // [wave][row][o pad 14->16] = 32 KB
    const int tid  = threadIdx.x;
    const int wave = tid >> 6;
    const int lane = tid & 63;
    const int col  = (wave << 8) | (lane << 2);   // wave = 256-col stripe

    float4 cmv[14];
    #pragma unroll
    for (int o = 0; o < 14; ++o)
        cmv[o] = *reinterpret_cast<const float4*>(cm + o * N0 + col);

    const int row0 = blockIdx.x * RPB;
    const float* xp = x + (size_t)row0 * N0 + col;

    float4 xb[BATCH];                      // 4 independent loads in flight
    #pragma unroll
    for (int j = 0; j < BATCH; ++j)
        xb[j] = *reinterpret_cast<const float4*>(xp + (size_t)j * N0);

    #pragma unroll 1
    for (int bt = 0; bt < NBATCH; ++bt) {
        float4 xn[BATCH];
        if (bt < NBATCH - 1) {
            #pragma unroll
            for (int j = 0; j < BATCH; ++j)
                xn[j] = *reinterpret_cast<const float4*>(
                            xp + (size_t)((bt + 1) * BATCH + j) * N0);
        }
        #pragma unroll
        for (int j = 0; j < BATCH; ++j) {
            const int r = bt * BATCH + j;
            const float4 xa = xb[j];

            // passthrough (out rows 8B-aligned -> float2 stores)
            float* orow = out + (size_t)(row0 + r) * OUTW + col;
            reinterpret_cast<float2*>(orow)[0] = make_float2(xa.x, xa.y);
            reinterpret_cast<float2*>(orow)[1] = make_float2(xa.z, xa.w);

            float red[14];
            #pragma unroll
            for (int o = 0; o < 14; ++o) {
                float v = xa.x * cmv[o].x;
                v = fmaf(xa.y, cmv[o].y, v);
                v = fmaf(xa.z, cmv[o].z, v);
                v = fmaf(xa.w, cmv[o].w, v);
                v = dpp_add<0xB1>(v);    // quad_perm [1,0,3,2]  (xor1)
                v = dpp_add<0x4E>(v);    // quad_perm [2,3,0,1]  (xor2)
                v = dpp_add<0x141>(v);   // row_half_mirror      (8-group)
                v = dpp_add<0x140>(v);   // row_mirror           (16-group)
                v += __shfl_xor(v, 16);
                v += __shfl_xor(v, 32);
                red[o] = v;
            }
            if (lane == 0) {
                float* p = &parts[wave][r][0];
                *reinterpret_cast<float4*>(p)      = make_float4(red[0], red[1], red[2], red[3]);
                *reinterpret_cast<float4*>(p + 4)  = make_float4(red[4], red[5], red[6], red[7]);
                *reinterpret_cast<float4*>(p + 8)  = make_float4(red[8], red[9], red[10], red[11]);
                *reinterpret_cast<float2*>(p + 12) = make_float2(red[12], red[13]);
            }
        }
        #pragma unroll
        for (int j = 0; j < BATCH; ++j) xb[j] = xn[j];
    }
    __syncthreads();

    // combine: 448 threads, one (row, o) each; fixed summation order.
    if (tid < RPB * 14) {
        const int r = tid / 14, o = tid - r * 14;
        float s = b[o];
        #pragma unroll
        for (int w = 0; w < 16; ++w) s += parts[w][r][o];
        out[(size_t)(row0 + r) * OUTW + N0 + o] = s;
    }
}

extern "C" void kernel_launch(void* const* d_in, const int* in_sizes, int n_in,
                              void* d_out, int out_size, void* d_ws, size_t ws_size,
                              hipStream_t stream) {
    const float* x = (const float*)d_in[0];   // [32,512,4096]
    const float* W = (const float*)d_in[1];   // [14,14]
    const float* b = (const float*)d_in[2];   // [14]
    float* out = (float*)d_out;               // [32,512,4110]
    float* cm  = (float*)d_ws;                // [14][4096]

    build_cm_kernel<<<14, 256, 0, stream>>>(W, cm);
    wavelet_aug_fused<<<ROWS / RPB, 1024, 0, stream>>>(x, cm, b, out);
}